// Round 1
// baseline (86.292 us; speedup 1.0000x reference)
//
#include <hip/hip_runtime.h>
#include <math.h>

#define EPSF 1e-9f
#define FOUR_PI 12.566370614359172f

// principal sqrt of (x + i*y) with y < 0 (y is always -4*pi*1e-9 here).
// Branchless, cancellation-free: compute the large component directly,
// derive the small one as y/(2*large).
__device__ __forceinline__ void csqrt_negim(float x, float y, float& u, float& v) {
    float r = sqrtf(fmaf(x, x, y * y));
    float w = sqrtf(0.5f * (r + fabsf(x)));   // large component, > 0
    float o = 0.5f * y / w;                   // small component, <= 0
    if (x >= 0.0f) { u = w;  v = o;  }        // u>0, v<=0
    else           { u = -o; v = -w; }        // u>=0 tiny, v<0
}

__global__ __launch_bounds__(256) void abeles_kernel(
    const float* __restrict__ qarr,   // B*Q
    const float* __restrict__ thick,  // B*L
    const float* __restrict__ rough,  // B*L
    const float* __restrict__ sld,    // B*(L+1)
    float* __restrict__ out,          // B*Q
    int Q, int L)
{
    const int b  = blockIdx.y;
    const int tx = threadIdx.x;
    const int iq = blockIdx.x * blockDim.x + tx;

    __shared__ float s_xp[65];   // 4*pi*1e-6*(sld[j]-sld[0]),  j=0..L
    __shared__ float s_t[64];    // thickness
    __shared__ float s_r2[64];   // roughness^2

    if (tx < L + 1) {
        float s0 = sld[b * (L + 1)];
        s_xp[tx] = (FOUR_PI * 1e-6f) * (sld[b * (L + 1) + tx] - s0);
    } else if (tx < 2 * L + 1) {
        int j = tx - (L + 1);
        s_t[j] = thick[b * L + j];
    } else if (tx < 3 * L + 1) {
        int j = tx - (2 * L + 1);
        float rr = rough[b * L + j];
        s_r2[j] = rr * rr;
    }
    __syncthreads();

    if (iq >= Q) return;

    const float Y = -(FOUR_PI * 1e-9f);       // constant imag part of k^2 argument
    float qh = 0.5f * qarr[b * Q + iq];
    float q2 = qh * qh;

    // k_0
    float u1, v1;
    csqrt_negim(q2 - s_xp[0], Y, u1, v1);

    // carry = identity (scan init is M_0; identity * M_0 == M_0)
    float ar = 1.0f, ai = 0.0f, br = 0.0f, bi = 0.0f;
    float cr = 0.0f, ci = 0.0f, dr = 1.0f, di = 0.0f;

    #pragma unroll 4
    for (int j = 0; j < L; ++j) {
        float u2, v2;
        csqrt_negim(q2 - s_xp[j + 1], Y, u2, v2);

        // fresnel r = (k1-k2)/(k1+k2+EPS)
        float nr = u1 - u2, ni = v1 - v2;
        float er = u1 + u2 + EPSF, ei = v1 + v2;
        float inv = 1.0f / fmaf(er, er, ei * ei);
        float rr = (nr * er + ni * ei) * inv;
        float ri = (ni * er - nr * ei) * inv;

        // roughness factor exp(-2*k1*k2*r^2)  (complex exponent)
        float kkr = u1 * u2 - v1 * v2;
        float kki = u1 * v2 + v1 * u2;
        float m2 = -2.0f * s_r2[j];
        float ew = __expf(m2 * kkr);
        float sw, cw;
        __sincosf(m2 * kki, &sw, &cw);
        float fr = ew * cw, fi = ew * sw;
        float trr = rr * fr - ri * fi;
        ri = rr * fi + ri * fr;
        rr = trr;

        // E = exp(i*t*k1) = e^{-t*v1} (cos(t*u1) + i sin(t*u1));  F = 1/E
        float t   = s_t[j];
        float mag = __expf(-t * v1);
        float img = 1.0f / mag;
        float sp, cp;
        __sincosf(t * u1, &sp, &cp);
        float Er = mag * cp, Ei = mag * sp;
        float Fr = img * cp, Fi = -img * sp;

        // rE, rF
        float rEr = rr * Er - ri * Ei, rEi = rr * Ei + ri * Er;
        float rFr = rr * Fr - ri * Fi, rFi = rr * Fi + ri * Fr;

        // carry = carry @ [[E, rE],[rF, F]]
        float nar = ar * Er - ai * Ei + br * rFr - bi * rFi;
        float nai = ar * Ei + ai * Er + br * rFi + bi * rFr;
        float nbr = ar * rEr - ai * rEi + br * Fr - bi * Fi;
        float nbi = ar * rEi + ai * rEr + br * Fi + bi * Fr;
        float ncr = cr * Er - ci * Ei + dr * rFr - di * rFi;
        float nci = cr * Ei + ci * Er + dr * rFi + di * rFr;
        float ndr = cr * rEr - ci * rEi + dr * Fr - di * Fi;
        float ndi = cr * rEi + ci * rEr + dr * Fi + di * Fr;
        ar = nar; ai = nai; br = nbr; bi = nbi;
        cr = ncr; ci = nci; dr = ndr; di = ndi;

        // overflow guard: product magnitudes can reach ~e^80; rescale.
        // quot = c/(a+EPS) is invariant to common scaling (up to EPS/|a|).
        float mx = fmaxf(fmaxf(fabsf(ar), fabsf(ai)), fmaxf(fabsf(cr), fabsf(ci)));
        mx = fmaxf(mx, fmaxf(fmaxf(fabsf(br), fabsf(bi)), fmaxf(fabsf(dr), fabsf(di))));
        if (mx > 1e18f) {
            const float s = 1e-18f;
            ar *= s; ai *= s; br *= s; bi *= s;
            cr *= s; ci *= s; dr *= s; di *= s;
        }

        u1 = u2; v1 = v2;
    }

    // quot = a10 / (a00 + EPS);  out = |quot|^2
    float aer = ar + EPSF;
    float inv = 1.0f / fmaf(aer, aer, ai * ai);
    float qr = (cr * aer + ci * ai) * inv;
    float qi = (ci * aer - cr * ai) * inv;
    out[b * Q + iq] = fmaf(qr, qr, qi * qi);
}

extern "C" void kernel_launch(void* const* d_in, const int* in_sizes, int n_in,
                              void* d_out, int out_size, void* d_ws, size_t ws_size,
                              hipStream_t stream) {
    const float* q     = (const float*)d_in[0];
    const float* thick = (const float*)d_in[1];
    const float* rough = (const float*)d_in[2];
    const float* sld   = (const float*)d_in[3];
    float* out = (float*)d_out;

    // B*(L+1) - B*L = B ;  L = (B*L)/B ;  Q = (B*Q)/B
    int B = in_sizes[3] - in_sizes[1];
    int L = in_sizes[1] / B;
    int Q = in_sizes[0] / B;

    dim3 block(256);
    dim3 grid((Q + 255) / 256, B);
    abeles_kernel<<<grid, block, 0, stream>>>(q, thick, rough, sld, out, Q, L);
}

// Round 2
// 37.174 us; speedup vs baseline: 2.3213x; 2.3213x over previous
//
#include <hip/hip_runtime.h>
#include <math.h>

#define EPSF 1e-9f
#define FOUR_PI 12.566370614359172f
#define YIM (-(FOUR_PI * 1e-9f))   // constant imag part of k^2 argument

__device__ __forceinline__ float frcp(float x) { return __builtin_amdgcn_rcpf(x); }
__device__ __forceinline__ float fsqrt(float x) { return __builtin_amdgcn_sqrtf(x); }

// principal sqrt of (x + i*Y) with Y < 0 constant.
// Cancellation-free: large component direct, small one as Y/(2*large).
__device__ __forceinline__ void csqrt_negim(float x, float& u, float& v) {
    float r = fsqrt(fmaf(x, x, YIM * YIM));
    float w = fsqrt(0.5f * (r + fabsf(x)));     // large component, > 0
    float o = (0.5f * YIM) * frcp(w);           // small component, <= 0
    if (x >= 0.0f) { u = w;  v = o;  }          // u>0, v<=0
    else           { u = -o; v = -w; }          // u>=0 tiny, v<0
}

// One Parratt step (layer j, iterating bottom-up):
//   r_j = fresnel(k_curr,k_next)*exp(-2 k_curr k_next sigma^2)
//   R   = e^{-2 i t k_curr} * (r_j + R) / (1 + r_j R)
// (un,vn) holds k_next on entry, k_curr on exit. |R| <= 1 always.
__device__ __forceinline__ void pstep(float q2, float xp, float t2, float m2,
                                      float& un, float& vn, float& Rr, float& Ri)
{
    float u1, v1;
    csqrt_negim(q2 - xp, u1, v1);
    float u2 = un, v2 = vn;

    // fresnel (k1-k2)/(k1+k2+EPS)
    float nr = u1 - u2, ni = v1 - v2;
    float er = u1 + u2 + EPSF, ei = v1 + v2;
    float inv = frcp(fmaf(er, er, ei * ei));
    float rr = (nr * er + ni * ei) * inv;
    float ri = (ni * er - nr * ei) * inv;

    // roughness factor exp(m2 * k1*k2), m2 = -2*sigma^2 (complex exponent)
    float kkr = u1 * u2 - v1 * v2;
    float kki = u1 * v2 + v1 * u2;
    float ew = __expf(m2 * kkr);
    float sw, cw;
    __sincosf(m2 * kki, &sw, &cw);
    float fr = ew * cw, fi = ew * sw;
    float tr = rr * fr - ri * fi;
    ri = fmaf(rr, fi, ri * fr);
    rr = tr;

    // Mobius: (r + R) / (1 + r*R)
    float numr = rr + Rr, numi = ri + Ri;
    float denr = fmaf(rr, Rr, fmaf(-ri, Ri, 1.0f));
    float deni = fmaf(rr, Ri, ri * Rr);
    float id = frcp(fmaf(denr, denr, deni * deni));
    float mr = (numr * denr + numi * deni) * id;
    float mi = (numi * denr - numr * deni) * id;

    // phase e^{-2 i t k1} = e^{t2*v1} (cos(t2*u1) - i sin(t2*u1)), t2 = 2t, v1<=0
    float pm = __expf(t2 * v1);
    float sp, cp;
    __sincosf(t2 * u1, &sp, &cp);
    float pr = pm * cp, pi = -pm * sp;
    Rr = mr * pr - mi * pi;
    Ri = mr * pi + mi * pr;

    un = u1; vn = v1;
}

__global__ __launch_bounds__(256) void abeles_kernel(
    const float* __restrict__ qarr,   // B*Q
    const float* __restrict__ thick,  // B*L
    const float* __restrict__ rough,  // B*L
    const float* __restrict__ sld,    // B*(L+1)
    float* __restrict__ out,          // B*Q
    int Q, int L)
{
    const int b  = blockIdx.y;
    const int tx = threadIdx.x;

    __shared__ float s_xp[65];   // 4*pi*1e-6*(sld[j]-sld[0]),  j=0..L
    __shared__ float s_t2[64];   // 2*thickness
    __shared__ float s_m2[64];   // -2*roughness^2

    if (tx < L + 1) {
        float s0 = sld[b * (L + 1)];
        s_xp[tx] = (FOUR_PI * 1e-6f) * (sld[b * (L + 1) + tx] - s0);
    } else if (tx < 2 * L + 1) {
        int j = tx - (L + 1);
        s_t2[j] = 2.0f * thick[b * L + j];
    } else if (tx < 3 * L + 1) {
        int j = tx - (2 * L + 1);
        float rr = rough[b * L + j];
        s_m2[j] = -2.0f * rr * rr;
    }
    __syncthreads();

    // two q-points per thread (independent chains fill latency stalls)
    const int iqA = blockIdx.x * (2 * blockDim.x) + tx;
    const int iqB = iqA + blockDim.x;
    const bool okA = iqA < Q, okB = iqB < Q;

    float qhA = okA ? 0.5f * qarr[b * Q + iqA] : 0.05f;
    float qhB = okB ? 0.5f * qarr[b * Q + iqB] : 0.05f;
    float q2A = qhA * qhA, q2B = qhB * qhB;

    // k at the substrate (layer L); R = 0
    float uA, vA, uB, vB;
    csqrt_negim(q2A - s_xp[L], uA, vA);
    csqrt_negim(q2B - s_xp[L], uB, vB);
    float RrA = 0.0f, RiA = 0.0f, RrB = 0.0f, RiB = 0.0f;

    #pragma unroll 4
    for (int j = L - 1; j >= 0; --j) {
        float xp = s_xp[j], t2 = s_t2[j], m2 = s_m2[j];
        pstep(q2A, xp, t2, m2, uA, vA, RrA, RiA);
        pstep(q2B, xp, t2, m2, uB, vB, RrB, RiB);
    }

    if (okA) out[b * Q + iqA] = fmaf(RrA, RrA, RiA * RiA);
    if (okB) out[b * Q + iqB] = fmaf(RrB, RrB, RiB * RiB);
}

extern "C" void kernel_launch(void* const* d_in, const int* in_sizes, int n_in,
                              void* d_out, int out_size, void* d_ws, size_t ws_size,
                              hipStream_t stream) {
    const float* q     = (const float*)d_in[0];
    const float* thick = (const float*)d_in[1];
    const float* rough = (const float*)d_in[2];
    const float* sld   = (const float*)d_in[3];
    float* out = (float*)d_out;

    int B = in_sizes[3] - in_sizes[1];   // B*(L+1) - B*L
    int L = in_sizes[1] / B;
    int Q = in_sizes[0] / B;

    dim3 block(256);
    dim3 grid((Q + 511) / 512, B);
    abeles_kernel<<<grid, block, 0, stream>>>(q, thick, rough, sld, out, Q, L);
}